// Round 14
// baseline (314.023 us; speedup 1.0000x reference)
//
#include <hip/hip_runtime.h>
#include <hip/hip_bf16.h>

#define BB 2
#define SS 2048
#define DD 1024
#define HH 16
#define HD 64

typedef __attribute__((ext_vector_type(8))) short bf16x8;
typedef __attribute__((ext_vector_type(4))) float f32x4;

// round-to-nearest-even f32 -> bf16 (inputs finite)
__device__ __forceinline__ unsigned short f2bf(float f) {
  unsigned int u = __float_as_uint(f);
  return (unsigned short)((u + 0x7FFFu + ((u >> 16) & 1u)) >> 16);
}

// 2^x via hardware v_exp_f32
__device__ __forceinline__ float fast_exp2(float x) {
#if __has_builtin(__builtin_amdgcn_exp2f)
  return __builtin_amdgcn_exp2f(x);
#else
  return __expf(x * 0.6931471805599453f);
#endif
}

__device__ __forceinline__ void async_copy16(const unsigned short* gp, unsigned short* lp) {
  __builtin_amdgcn_global_load_lds(
      (const __attribute__((address_space(1))) unsigned int*)gp,
      (__attribute__((address_space(3))) unsigned int*)lp, 16, 0, 0);
}

// ---------------------------------------------------------------------------
// Fused prep: blocks [0,4096) convert x -> bf16; blocks [4096,8192) transpose
// one of the 4 weight matrices (1024 32x32 tiles each) to bf16 [N][K].
// ---------------------------------------------------------------------------
__global__ __launch_bounds__(256) void prep_kernel(
    const float* __restrict__ x, unsigned short* __restrict__ xb,
    const float* __restrict__ W0, unsigned short* __restrict__ T0,
    const float* __restrict__ W1, unsigned short* __restrict__ T1,
    const float* __restrict__ W2, unsigned short* __restrict__ T2,
    const float* __restrict__ W3, unsigned short* __restrict__ T3) {
  const int blk = blockIdx.x;
  const int t = threadIdx.x;
  if (blk < 4096) {
    int i = blk * 1024 + t * 4;
    float4 v = *(const float4*)(x + i);
    ushort4 u;
    u.x = f2bf(v.x); u.y = f2bf(v.y); u.z = f2bf(v.z); u.w = f2bf(v.w);
    *(ushort4*)(xb + i) = u;
    return;
  }
  const int j = blk - 4096;
  const int jw = j >> 10;          // which weight
  const int tb = j & 1023;
  const float* W = jw == 0 ? W0 : (jw == 1 ? W1 : (jw == 2 ? W2 : W3));
  unsigned short* T = jw == 0 ? T0 : (jw == 1 ? T1 : (jw == 2 ? T2 : T3));
  __shared__ float tile[32][33];
  int k0 = (tb & 31) * 32, n0 = (tb >> 5) * 32;
  int c = t & 31, r0 = t >> 5;
#pragma unroll
  for (int i = 0; i < 4; ++i) {
    int r = r0 + i * 8;
    tile[r][c] = W[(size_t)(k0 + r) * DD + n0 + c];
  }
  __syncthreads();
#pragma unroll
  for (int i = 0; i < 4; ++i) {
    int r = r0 + i * 8;
    T[(size_t)(n0 + r) * DD + k0 + c] = f2bf(tile[c][r]);
  }
}

// ---------------------------------------------------------------------------
// bf16 MFMA GEMM core, VGPR-prefetch single-LDS pipeline:
//   barrier1 -> issue buffer_loads(it+1) -> ds_read frags -> 16 MFMA
//   -> barrier2 -> ds_write prefetched tile (addr includes +l*8 per-lane
//   offset — R13's NaN was this offset missing: all 64 lanes stored to the
//   same 16 B; global_load_lds adds lane*16B in HW, manual stores must not
//   drop it).
// D = A[M,K]@B^T[N,K] + bias.
// STORE=0: fp32 out [M][DD]
// STORE=1: bf16 out [B,H,S,HD], value scaled (Q: 0.125*log2e, K: 1)
// STORE=2: bf16 out [B,H,HD,S] (V transposed), LDS-transposed coalesced store
// ---------------------------------------------------------------------------
template <int STORE>
__device__ __forceinline__ void gemm_core(
    const unsigned short* __restrict__ A, const unsigned short* __restrict__ BT,
    const float* __restrict__ bias, void* __restrict__ outp, float scale,
    int bm, int bn) {
  const int t = threadIdx.x;
  const int w = t >> 6;
  const int l = t & 63;
  const int wm = (w >> 1) * 64;
  const int wn = (w & 1) * 64;

  __shared__ __align__(16) unsigned short As[128 * 32];
  __shared__ __align__(16) unsigned short Bs[128 * 32];

  f32x4 acc[4][4];
#pragma unroll
  for (int i = 0; i < 4; ++i)
#pragma unroll
    for (int j = 0; j < 4; ++j) acc[i][j] = (f32x4)0.f;

  const int fr = l & 15;
  const int kg = (l >> 4) * 8;

  // staging geometry: thread covers chunks c=0,1 of A and B (16B each)
  int srow[2], skk[2];
#pragma unroll
  for (int c = 0; c < 2; ++c) {
    int e = (w * 2 + c) * 512 + l * 8;
    srow[c] = e >> 5;
    skk[c] = e & 31;
  }

  uint4 pa[2], pb[2];
  // preload tile 0 into VGPRs, then LDS (visible after first barrier)
#pragma unroll
  for (int c = 0; c < 2; ++c) {
    pa[c] = *(const uint4*)(A + (size_t)(bm + srow[c]) * DD + skk[c]);
    pb[c] = *(const uint4*)(BT + (size_t)(bn + srow[c]) * DD + skk[c]);
  }
#pragma unroll
  for (int c = 0; c < 2; ++c) {
    *(uint4*)(As + (w * 2 + c) * 512 + l * 8) = pa[c];
    *(uint4*)(Bs + (w * 2 + c) * 512 + l * 8) = pb[c];
  }

  for (int it = 0; it < DD / 32; ++it) {
    __syncthreads();  // prefetched LDS writes visible; prior reads done

    // issue next tile's global loads first (max latency overlap)
    if (it + 1 < DD / 32) {
      int k0 = (it + 1) * 32;
#pragma unroll
      for (int c = 0; c < 2; ++c) {
        pa[c] = *(const uint4*)(A + (size_t)(bm + srow[c]) * DD + k0 + skk[c]);
        pb[c] = *(const uint4*)(BT + (size_t)(bn + srow[c]) * DD + k0 + skk[c]);
      }
    }

    bf16x8 af[4], bfr[4];
#pragma unroll
    for (int i = 0; i < 4; ++i)
      af[i] = *(const bf16x8*)(As + (wm + i * 16 + fr) * 32 + kg);
#pragma unroll
    for (int j = 0; j < 4; ++j)
      bfr[j] = *(const bf16x8*)(Bs + (wn + j * 16 + fr) * 32 + kg);
#pragma unroll
    for (int i = 0; i < 4; ++i)
#pragma unroll
      for (int j = 0; j < 4; ++j)
        acc[i][j] = __builtin_amdgcn_mfma_f32_16x16x32_bf16(af[i], bfr[j], acc[i][j], 0, 0, 0);

    __syncthreads();  // all waves done reading As/Bs (lgkm-only drain)
    if (it + 1 < DD / 32) {
#pragma unroll
      for (int c = 0; c < 2; ++c) {
        *(uint4*)(As + (w * 2 + c) * 512 + l * 8) = pa[c];  // vmcnt wait here,
        *(uint4*)(Bs + (w * 2 + c) * 512 + l * 8) = pb[c];  // hidden by MFMAs
      }
    }
  }

  const int col_l = l & 15;
  const int row_l = (l >> 4) * 4;

  if (STORE == 2) {
    // Transpose 128x128 C tile via LDS (4 passes of 32 n-cols), then store
    // VbT[(b*HH+h)*HD+hd][s] with 256 B contiguous runs along s.
    unsigned short* out = (unsigned short*)outp;
    unsigned int* T = (unsigned int*)As;  // 2048 dwords
    const int b_ = bm >> 11;
    const int srow0 = bm & 2047;          // within-batch S offset
#pragma unroll
    for (int p = 0; p < 4; ++p) {
      __syncthreads();  // As free (K-loop done / previous pass read done)
      if ((w & 1) == (p >> 1)) {
        const int jt0 = (p & 1) * 2;
#pragma unroll
        for (int jj = 0; jj < 2; ++jj) {
          int jt = jt0 + jj;
          int n_p = jj * 16 + col_l;          // n within pass [0,32)
          float bv = bias[bn + p * 32 + n_p];
#pragma unroll
          for (int i = 0; i < 4; ++i) {
            int m0 = wm + i * 16 + row_l;     // even
#pragma unroll
            for (int pr = 0; pr < 2; ++pr) {
              unsigned int val =
                  (unsigned int)f2bf(acc[i][jt][2 * pr] + bv) |
                  ((unsigned int)f2bf(acc[i][jt][2 * pr + 1] + bv) << 16);
              int m = m0 + 2 * pr;
              T[n_p * 64 + (((m >> 1)) ^ ((n_p & 7) << 2))] = val;
            }
          }
        }
      }
      __syncthreads();
#pragma unroll
      for (int c = 0; c < 2; ++c) {
        int q = t + c * 256;
        int n_p = q >> 4, cpos = q & 15;
        uint4 v = *(const uint4*)(T + n_p * 64 + ((cpos * 4) ^ ((n_p & 7) << 2)));
        int n_glob = bn + p * 32 + n_p;
        int h_ = n_glob >> 6, hd_ = n_glob & 63;
        *(uint4*)(out + ((size_t)((b_ * HH + h_) * HD + hd_)) * SS + srow0 + cpos * 8) = v;
      }
    }
    return;
  }

#pragma unroll
  for (int i = 0; i < 4; ++i) {
    int m_base = bm + wm + i * 16 + row_l;
#pragma unroll
    for (int j = 0; j < 4; ++j) {
      int n = bn + wn + j * 16 + col_l;
      float bv = bias[n];
      if (STORE == 0) {
        float* out = (float*)outp;
#pragma unroll
        for (int r = 0; r < 4; ++r)
          out[(size_t)(m_base + r) * DD + n] = acc[i][j][r] + bv;
      } else {
        unsigned short* out = (unsigned short*)outp;
        int h_ = n >> 6, hd_ = n & 63;
#pragma unroll
        for (int r = 0; r < 4; ++r) {
          int m = m_base + r;
          int b_ = m >> 11, s_ = m & 2047;
          out[(((size_t)(b_ * HH + h_) * SS) + s_) * HD + hd_] =
              f2bf((acc[i][j][r] + bv) * scale);
        }
      }
    }
  }
}

// Fused QKV projection, 768 blocks, XCD-swizzled.
__global__ __launch_bounds__(256) void qkv_gemm_mfma(
    const unsigned short* __restrict__ A,
    const unsigned short* __restrict__ WqT, const unsigned short* __restrict__ WkT,
    const unsigned short* __restrict__ WvT,
    const float* __restrict__ bq, const float* __restrict__ bk,
    const float* __restrict__ bv,
    unsigned short* __restrict__ Qo, unsigned short* __restrict__ Ko,
    unsigned short* __restrict__ VTo) {
  const int i = blockIdx.x;
  const int xcd = i & 7;
  const int slot = i >> 3;            // 0..95
  const int bm = (xcd + 8 * (slot / 24)) * 128;
  const int c = slot % 24;
  const int which = c >> 3;
  const int bn = (c & 7) * 128;
  if (which == 0)
    gemm_core<1>(A, WqT, bq, (void*)Qo, 0.18033688011112042f, bm, bn);
  else if (which == 1)
    gemm_core<1>(A, WkT, bk, (void*)Ko, 1.0f, bm, bn);
  else
    gemm_core<2>(A, WvT, bv, (void*)VTo, 1.0f, bm, bn);
}

// output projection, 256 blocks, XCD-swizzled.
__global__ __launch_bounds__(256) void out_gemm_mfma(
    const unsigned short* __restrict__ A, const unsigned short* __restrict__ WoT,
    const float* __restrict__ bo, float* __restrict__ out) {
  const int i = blockIdx.x;
  const int xcd = i & 7;
  const int slot = i >> 3;            // 0..31
  const int bm = (xcd + 8 * (slot >> 3)) * 128;
  const int bn = (slot & 7) * 128;
  gemm_core<0>(A, WoT, bo, (void*)out, 1.0f, bm, bn);
}

// ---------------------------------------------------------------------------
// MFMA flash attention v6 (R11, unchanged): Q-tile 128, dbuf K/V staging,
// P C->B layout conversion via wave-private LDS scratch.
// ---------------------------------------------------------------------------
__global__ __launch_bounds__(256) void flash_attn_mfma(
    const unsigned short* __restrict__ Q,   // [B,H,S,HD] bf16 (pre-scaled)
    const unsigned short* __restrict__ K,   // [B,H,S,HD] bf16
    const unsigned short* __restrict__ VT,  // [B,H,HD,S] bf16
    unsigned short* __restrict__ ctx) {     // [B,S,D] bf16
  const int bh = blockIdx.x;
  const int qt = blockIdx.y;
  const int b  = bh >> 4;
  const int h  = bh & 15;
  const int t  = threadIdx.x;
  const int w  = t >> 6;   // wave 0..3
  const int l  = t & 63;
  const int g  = l >> 4;   // lane group 0..3
  const int ln = l & 15;   // q index within n-tile

  const unsigned short* Qp = Q + ((size_t)bh * SS + (size_t)qt * 128 + w * 32) * HD;
  const unsigned short* Kp = K + (size_t)bh * SS * HD;
  const unsigned short* Vp = VT + (size_t)bh * HD * SS;

  __shared__ __align__(16) unsigned short Ks[2][64 * 64];  // [key][hd], swizzled
  __shared__ __align__(16) unsigned short Vs[2][64 * 64];  // [hd][key], swizzled
  __shared__ __align__(16) unsigned short Ps[4][32 * 64];  // per-wave P scratch

  bf16x8 qf[2][2];
#pragma unroll
  for (int nt = 0; nt < 2; ++nt)
#pragma unroll
    for (int kb = 0; kb < 2; ++kb)
      qf[nt][kb] = *(const bf16x8*)(Qp + (nt * 16 + ln) * HD + kb * 32 + g * 8);

  f32x4 o[2][4];
#pragma unroll
  for (int nt = 0; nt < 2; ++nt)
#pragma unroll
    for (int mt = 0; mt < 4; ++mt) o[nt][mt] = (f32x4)0.f;
  float rs[2] = {0.f, 0.f};

  char* pw = (char*)&Ps[w][0];

  auto stage = [&](int kt, int half) {
#pragma unroll
    for (int j = 0; j < 2; ++j) {
      int c = (w * 2 + j) * 64 + l;
      int row = c >> 3, cc = c & 7;
      int gcc = cc ^ (row & 7);
      async_copy16(Kp + (size_t)(kt * 64 + row) * HD + gcc * 8,
                   &Ks[half][(w * 2 + j) * 512]);
      async_copy16(Vp + (size_t)row * SS + kt * 64 + gcc * 8,
                   &Vs[half][(w * 2 + j) * 512]);
    }
  };

  stage(0, 0);
  for (int kt = 0; kt < SS / 64; ++kt) {
    const int half = kt & 1;
    __syncthreads();
    if (kt + 1 < SS / 64) stage(kt + 1, half ^ 1);

    f32x4 st[2][4];
#pragma unroll
    for (int nt = 0; nt < 2; ++nt)
#pragma unroll
      for (int mt = 0; mt < 4; ++mt) st[nt][mt] = (f32x4)0.f;
#pragma unroll
    for (int kb = 0; kb < 2; ++kb)
#pragma unroll
      for (int mt = 0; mt < 4; ++mt) {
        int row = mt * 16 + ln;
        bf16x8 ka = *(const bf16x8*)(&Ks[half][row * 64 + (((kb * 4 + g) ^ (row & 7)) * 8)]);
        st[0][mt] = __builtin_amdgcn_mfma_f32_16x16x32_bf16(ka, qf[0][kb], st[0][mt], 0, 0, 0);
        st[1][mt] = __builtin_amdgcn_mfma_f32_16x16x32_bf16(ka, qf[1][kb], st[1][mt], 0, 0, 0);
      }

    // p = exp2(s'); pack bf16 pairs; write P to wave-private LDS scratch
#pragma unroll
    for (int nt = 0; nt < 2; ++nt) {
      const int q = nt * 16 + ln;
      const int qs = q & 7;
#pragma unroll
      for (int mt = 0; mt < 4; ++mt) {
        float p0 = fast_exp2(st[nt][mt][0]);
        float p1 = fast_exp2(st[nt][mt][1]);
        float p2 = fast_exp2(st[nt][mt][2]);
        float p3 = fast_exp2(st[nt][mt][3]);
        uint2 v2;
        v2.x = __builtin_amdgcn_perm(__float_as_uint(p1), __float_as_uint(p0), 0x07060302u);
        v2.y = __builtin_amdgcn_perm(__float_as_uint(p3), __float_as_uint(p2), 0x07060302u);
        rs[nt] += (p0 + p1) + (p2 + p3);
        int chunk = (2 * mt + (g >> 1)) ^ qs;
        *(uint2*)(pw + q * 128 + chunk * 16 + (g & 1) * 8) = v2;
      }
    }

#pragma unroll
    for (int kb = 0; kb < 2; ++kb) {
      bf16x8 pbv[2];
#pragma unroll
      for (int nt = 0; nt < 2; ++nt) {
        const int q = nt * 16 + ln;
        int chunk = (4 * kb + g) ^ (q & 7);
        pbv[nt] = *(const bf16x8*)(pw + q * 128 + chunk * 16);
      }
#pragma unroll
      for (int mt = 0; mt < 4; ++mt) {
        int row = mt * 16 + ln;
        bf16x8 va = *(const bf16x8*)(&Vs[half][row * 64 + (((kb * 4 + g) ^ (row & 7)) * 8)]);
        o[0][mt] = __builtin_amdgcn_mfma_f32_16x16x32_bf16(va, pbv[0], o[0][mt], 0, 0, 0);
        o[1][mt] = __builtin_amdgcn_mfma_f32_16x16x32_bf16(va, pbv[1], o[1][mt], 0, 0, 0);
      }
    }
  }

#pragma unroll
  for (int nt = 0; nt < 2; ++nt) {
    float lsum = rs[nt];
    lsum += __shfl_xor(lsum, 16, 64);
    lsum += __shfl_xor(lsum, 32, 64);
    float inv = 1.f / lsum;
    int srow = qt * 128 + w * 32 + nt * 16 + ln;
    unsigned short* cb = ctx + (size_t)(b * SS + srow) * DD + h * HD;
#pragma unroll
    for (int mt = 0; mt < 4; ++mt) {
      ushort4 u4;
      u4.x = f2bf(o[nt][mt][0] * inv);
      u4.y = f2bf(o[nt][mt][1] * inv);
      u4.z = f2bf(o[nt][mt][2] * inv);
      u4.w = f2bf(o[nt][mt][3] * inv);
      *(ushort4*)(cb + mt * 16 + 4 * g) = u4;
    }
  }
}

// ---------------------------------------------------------------------------
extern "C" void kernel_launch(void* const* d_in, const int* in_sizes, int n_in,
                              void* d_out, int out_size, void* d_ws, size_t ws_size,
                              hipStream_t stream) {
  const float* x  = (const float*)d_in[0];
  const float* Wq = (const float*)d_in[1];
  const float* bq = (const float*)d_in[2];
  const float* Wk = (const float*)d_in[3];
  const float* bk = (const float*)d_in[4];
  const float* Wv = (const float*)d_in[5];
  const float* bv = (const float*)d_in[6];
  const float* Wo = (const float*)d_in[7];
  const float* bo = (const float*)d_in[8];
  float* out = (float*)d_out;

  const size_t ELEMS = (size_t)BB * SS * DD;  // 4,194,304
  char* ws = (char*)d_ws;
  unsigned short* xb   = (unsigned short*)ws;  ws += ELEMS * 2;
  unsigned short* WqT  = (unsigned short*)ws;  ws += (size_t)DD * DD * 2;
  unsigned short* WkT  = (unsigned short*)ws;  ws += (size_t)DD * DD * 2;
  unsigned short* WvT  = (unsigned short*)ws;  ws += (size_t)DD * DD * 2;
  unsigned short* WoT  = (unsigned short*)ws;  ws += (size_t)DD * DD * 2;
  unsigned short* Qb   = (unsigned short*)ws;  ws += ELEMS * 2;
  unsigned short* Kb   = (unsigned short*)ws;  ws += ELEMS * 2;
  unsigned short* VbT  = (unsigned short*)ws;  ws += ELEMS * 2;
  unsigned short* ctxb = (unsigned short*)ws;  ws += ELEMS * 2;

  // fused prep: x->bf16 (4096 blocks) + 4 weight transposes (4096 blocks)
  prep_kernel<<<8192, 256, 0, stream>>>(x, xb, Wq, WqT, Wk, WkT, Wv, WvT, Wo, WoT);

  qkv_gemm_mfma<<<768, 256, 0, stream>>>(xb, WqT, WkT, WvT, bq, bk, bv,
                                         Qb, Kb, VbT);

  dim3 attn_grid(BB * HH, SS / 128);           // (32, 16) = 512 blocks
  flash_attn_mfma<<<attn_grid, 256, 0, stream>>>(Qb, Kb, VbT, ctxb);

  out_gemm_mfma<<<256, 256, 0, stream>>>(ctxb, WoT, bo, out);
}

// Round 15
// 220.390 us; speedup vs baseline: 1.4248x; 1.4248x over previous
//
#include <hip/hip_runtime.h>
#include <hip/hip_bf16.h>

#define BB 2
#define SS 2048
#define DD 1024
#define HH 16
#define HD 64

typedef __attribute__((ext_vector_type(8))) short bf16x8;
typedef __attribute__((ext_vector_type(4))) float f32x4;

// round-to-nearest-even f32 -> bf16 (inputs finite)
__device__ __forceinline__ unsigned short f2bf(float f) {
  unsigned int u = __float_as_uint(f);
  return (unsigned short)((u + 0x7FFFu + ((u >> 16) & 1u)) >> 16);
}

// 2^x via hardware v_exp_f32
__device__ __forceinline__ float fast_exp2(float x) {
#if __has_builtin(__builtin_amdgcn_exp2f)
  return __builtin_amdgcn_exp2f(x);
#else
  return __expf(x * 0.6931471805599453f);
#endif
}

__device__ __forceinline__ void async_copy16(const unsigned short* gp, unsigned short* lp) {
  __builtin_amdgcn_global_load_lds(
      (const __attribute__((address_space(1))) unsigned int*)gp,
      (__attribute__((address_space(3))) unsigned int*)lp, 16, 0, 0);
}

// ---------------------------------------------------------------------------
// Fused prep: blocks [0,4096) convert x -> bf16; blocks [4096,8192) transpose
// one of the 4 weight matrices (1024 32x32 tiles each) to bf16 [N][K].
// ---------------------------------------------------------------------------
__global__ __launch_bounds__(256) void prep_kernel(
    const float* __restrict__ x, unsigned short* __restrict__ xb,
    const float* __restrict__ W0, unsigned short* __restrict__ T0,
    const float* __restrict__ W1, unsigned short* __restrict__ T1,
    const float* __restrict__ W2, unsigned short* __restrict__ T2,
    const float* __restrict__ W3, unsigned short* __restrict__ T3) {
  const int blk = blockIdx.x;
  const int t = threadIdx.x;
  if (blk < 4096) {
    int i = blk * 1024 + t * 4;
    float4 v = *(const float4*)(x + i);
    ushort4 u;
    u.x = f2bf(v.x); u.y = f2bf(v.y); u.z = f2bf(v.z); u.w = f2bf(v.w);
    *(ushort4*)(xb + i) = u;
    return;
  }
  const int j = blk - 4096;
  const int jw = j >> 10;          // which weight
  const int tb = j & 1023;
  const float* W = jw == 0 ? W0 : (jw == 1 ? W1 : (jw == 2 ? W2 : W3));
  unsigned short* T = jw == 0 ? T0 : (jw == 1 ? T1 : (jw == 2 ? T2 : T3));
  __shared__ float tile[32][33];
  int k0 = (tb & 31) * 32, n0 = (tb >> 5) * 32;
  int c = t & 31, r0 = t >> 5;
#pragma unroll
  for (int i = 0; i < 4; ++i) {
    int r = r0 + i * 8;
    tile[r][c] = W[(size_t)(k0 + r) * DD + n0 + c];
  }
  __syncthreads();
#pragma unroll
  for (int i = 0; i < 4; ++i) {
    int r = r0 + i * 8;
    T[(size_t)(n0 + r) * DD + k0 + c] = f2bf(tile[c][r]);
  }
}

// ---------------------------------------------------------------------------
// bf16 MFMA GEMM core (m97 single-buffer global_load_lds K-loop — the
// VGPR-prefetch variant of R13/R14 measured 2x slower; reverted).
// D = A[M,K]@B^T[N,K] + bias.
// STORE=0: fp32 out [M][DD] (full 64B-line stores already)
// STORE=1: bf16 out [B,H,S,HD], scaled; NEW: LDS-staged coalesced epilogue —
//          C tile -> Cs[m][72 pad] -> full 128B-aligned (s,h) row stores.
//          (R14 counters: scattered 2B stores caused WRITE 84MB vs 24 ideal.)
// STORE=2: bf16 out [B,H,HD,S] (V transposed), LDS-transposed coalesced store
// ---------------------------------------------------------------------------
template <int STORE>
__device__ __forceinline__ void gemm_core(
    const unsigned short* __restrict__ A, const unsigned short* __restrict__ BT,
    const float* __restrict__ bias, void* __restrict__ outp, float scale,
    int bm, int bn) {
  const int t = threadIdx.x;
  const int w = t >> 6;
  const int l = t & 63;
  const int wm = (w >> 1) * 64;
  const int wn = (w & 1) * 64;

  // pool: As=[0,4096), Bs=[4096,8192) ushorts; STORE=1 epilogue reuses the
  // whole pool as Cs[128][72] (9216 ushorts, 18.4 KB).
  __shared__ __align__(16) unsigned short pool[9216];
  unsigned short* As = pool;
  unsigned short* Bs = pool + 4096;

  f32x4 acc[4][4];
#pragma unroll
  for (int i = 0; i < 4; ++i)
#pragma unroll
    for (int j = 0; j < 4; ++j) acc[i][j] = (f32x4)0.f;

  const int fr = l & 15;
  const int kg = (l >> 4) * 8;

  for (int k0 = 0; k0 < DD; k0 += 32) {
    __syncthreads();
#pragma unroll
    for (int c = 0; c < 2; ++c) {
      int e = (w * 2 + c) * 512 + l * 8;
      int row = e >> 5, kk = e & 31;
      async_copy16(A + (size_t)(bm + row) * DD + k0 + kk, As + (w * 2 + c) * 512);
      async_copy16(BT + (size_t)(bn + row) * DD + k0 + kk, Bs + (w * 2 + c) * 512);
    }
    __syncthreads();

    bf16x8 af[4], bfr[4];
#pragma unroll
    for (int i = 0; i < 4; ++i)
      af[i] = *(const bf16x8*)(As + (wm + i * 16 + fr) * 32 + kg);
#pragma unroll
    for (int j = 0; j < 4; ++j)
      bfr[j] = *(const bf16x8*)(Bs + (wn + j * 16 + fr) * 32 + kg);
#pragma unroll
    for (int i = 0; i < 4; ++i)
#pragma unroll
      for (int j = 0; j < 4; ++j)
        acc[i][j] = __builtin_amdgcn_mfma_f32_16x16x32_bf16(af[i], bfr[j], acc[i][j], 0, 0, 0);
  }

  const int col_l = l & 15;
  const int row_l = (l >> 4) * 4;

  if (STORE == 1) {
    // Coalesced [B,H,S,HD] store via LDS: 2 passes over n-halves (one h each).
    // Pass p: waves with wn==p*64 write their acc into Cs[m][n&63] (padded 72
    // for bank spread), then all threads store full 128 B (s,h) rows (uint4,
    // 8 lanes/row, 4 KB contiguous per round).
    unsigned short* out = (unsigned short*)outp;
    unsigned short* Cs = pool;            // 128*72 ushorts
    const int b_ = bm >> 11;
    const int s0 = bm & 2047;
    const int h0 = bn >> 6;
#pragma unroll
    for (int p = 0; p < 2; ++p) {
      __syncthreads();  // pool free (K-loop / previous pass reads done)
      if ((w & 1) == p) {
#pragma unroll
        for (int j = 0; j < 4; ++j) {
          int n_loc = j * 16 + col_l;
          float bv = bias[bn + p * 64 + n_loc];
#pragma unroll
          for (int i = 0; i < 4; ++i)
#pragma unroll
            for (int r = 0; r < 4; ++r)
              Cs[(wm + i * 16 + row_l + r) * 72 + n_loc] =
                  f2bf((acc[i][j][r] + bv) * scale);
        }
      }
      __syncthreads();
      const size_t obase = ((size_t)(b_ * HH + h0 + p) * SS + s0) * HD;
#pragma unroll
      for (int rnd = 0; rnd < 4; ++rnd) {
        int m = rnd * 32 + (t >> 3);
        int c = t & 7;
        uint4 v = *(const uint4*)(Cs + m * 72 + c * 8);
        *(uint4*)(out + obase + (size_t)m * HD + c * 8) = v;
      }
    }
    return;
  }

  if (STORE == 2) {
    // Transpose 128x128 C tile via LDS (4 passes of 32 n-cols), then store
    // VbT[(b*HH+h)*HD+hd][s] with 256 B contiguous runs along s.
    unsigned short* out = (unsigned short*)outp;
    unsigned int* T = (unsigned int*)As;  // 2048 dwords
    const int b_ = bm >> 11;
    const int srow0 = bm & 2047;          // within-batch S offset
#pragma unroll
    for (int p = 0; p < 4; ++p) {
      __syncthreads();  // As free (K-loop done / previous pass read done)
      if ((w & 1) == (p >> 1)) {
        const int jt0 = (p & 1) * 2;
#pragma unroll
        for (int jj = 0; jj < 2; ++jj) {
          int jt = jt0 + jj;
          int n_p = jj * 16 + col_l;          // n within pass [0,32)
          float bv = bias[bn + p * 32 + n_p];
#pragma unroll
          for (int i = 0; i < 4; ++i) {
            int m0 = wm + i * 16 + row_l;     // even
#pragma unroll
            for (int pr = 0; pr < 2; ++pr) {
              unsigned int val =
                  (unsigned int)f2bf(acc[i][jt][2 * pr] + bv) |
                  ((unsigned int)f2bf(acc[i][jt][2 * pr + 1] + bv) << 16);
              int m = m0 + 2 * pr;
              T[n_p * 64 + (((m >> 1)) ^ ((n_p & 7) << 2))] = val;
            }
          }
        }
      }
      __syncthreads();
#pragma unroll
      for (int c = 0; c < 2; ++c) {
        int q = t + c * 256;
        int n_p = q >> 4, cpos = q & 15;
        uint4 v = *(const uint4*)(T + n_p * 64 + ((cpos * 4) ^ ((n_p & 7) << 2)));
        int n_glob = bn + p * 32 + n_p;
        int h_ = n_glob >> 6, hd_ = n_glob & 63;
        *(uint4*)(out + ((size_t)((b_ * HH + h_) * HD + hd_)) * SS + srow0 + cpos * 8) = v;
      }
    }
    return;
  }

  // STORE == 0: fp32 [M][DD]; lanes cover 64 consecutive n*4B = full lines.
#pragma unroll
  for (int i = 0; i < 4; ++i) {
    int m_base = bm + wm + i * 16 + row_l;
#pragma unroll
    for (int j = 0; j < 4; ++j) {
      int n = bn + wn + j * 16 + col_l;
      float bv = bias[n];
      float* out = (float*)outp;
#pragma unroll
      for (int r = 0; r < 4; ++r)
        out[(size_t)(m_base + r) * DD + n] = acc[i][j][r] + bv;
    }
  }
}

// Fused QKV projection, 768 blocks, XCD-swizzled.
__global__ __launch_bounds__(256) void qkv_gemm_mfma(
    const unsigned short* __restrict__ A,
    const unsigned short* __restrict__ WqT, const unsigned short* __restrict__ WkT,
    const unsigned short* __restrict__ WvT,
    const float* __restrict__ bq, const float* __restrict__ bk,
    const float* __restrict__ bv,
    unsigned short* __restrict__ Qo, unsigned short* __restrict__ Ko,
    unsigned short* __restrict__ VTo) {
  const int i = blockIdx.x;
  const int xcd = i & 7;
  const int slot = i >> 3;            // 0..95
  const int bm = (xcd + 8 * (slot / 24)) * 128;
  const int c = slot % 24;
  const int which = c >> 3;
  const int bn = (c & 7) * 128;
  if (which == 0)
    gemm_core<1>(A, WqT, bq, (void*)Qo, 0.18033688011112042f, bm, bn);
  else if (which == 1)
    gemm_core<1>(A, WkT, bk, (void*)Ko, 1.0f, bm, bn);
  else
    gemm_core<2>(A, WvT, bv, (void*)VTo, 1.0f, bm, bn);
}

// output projection, 256 blocks, XCD-swizzled.
__global__ __launch_bounds__(256) void out_gemm_mfma(
    const unsigned short* __restrict__ A, const unsigned short* __restrict__ WoT,
    const float* __restrict__ bo, float* __restrict__ out) {
  const int i = blockIdx.x;
  const int xcd = i & 7;
  const int slot = i >> 3;            // 0..31
  const int bm = (xcd + 8 * (slot >> 3)) * 128;
  const int bn = (slot & 7) * 128;
  gemm_core<0>(A, WoT, bo, (void*)out, 1.0f, bm, bn);
}

// ---------------------------------------------------------------------------
// MFMA flash attention v6 (R11, unchanged): Q-tile 128, dbuf K/V staging,
// P C->B layout conversion via wave-private LDS scratch.
// ---------------------------------------------------------------------------
__global__ __launch_bounds__(256) void flash_attn_mfma(
    const unsigned short* __restrict__ Q,   // [B,H,S,HD] bf16 (pre-scaled)
    const unsigned short* __restrict__ K,   // [B,H,S,HD] bf16
    const unsigned short* __restrict__ VT,  // [B,H,HD,S] bf16
    unsigned short* __restrict__ ctx) {     // [B,S,D] bf16
  const int bh = blockIdx.x;
  const int qt = blockIdx.y;
  const int b  = bh >> 4;
  const int h  = bh & 15;
  const int t  = threadIdx.x;
  const int w  = t >> 6;   // wave 0..3
  const int l  = t & 63;
  const int g  = l >> 4;   // lane group 0..3
  const int ln = l & 15;   // q index within n-tile

  const unsigned short* Qp = Q + ((size_t)bh * SS + (size_t)qt * 128 + w * 32) * HD;
  const unsigned short* Kp = K + (size_t)bh * SS * HD;
  const unsigned short* Vp = VT + (size_t)bh * HD * SS;

  __shared__ __align__(16) unsigned short Ks[2][64 * 64];  // [key][hd], swizzled
  __shared__ __align__(16) unsigned short Vs[2][64 * 64];  // [hd][key], swizzled
  __shared__ __align__(16) unsigned short Ps[4][32 * 64];  // per-wave P scratch

  bf16x8 qf[2][2];
#pragma unroll
  for (int nt = 0; nt < 2; ++nt)
#pragma unroll
    for (int kb = 0; kb < 2; ++kb)
      qf[nt][kb] = *(const bf16x8*)(Qp + (nt * 16 + ln) * HD + kb * 32 + g * 8);

  f32x4 o[2][4];
#pragma unroll
  for (int nt = 0; nt < 2; ++nt)
#pragma unroll
    for (int mt = 0; mt < 4; ++mt) o[nt][mt] = (f32x4)0.f;
  float rs[2] = {0.f, 0.f};

  char* pw = (char*)&Ps[w][0];

  auto stage = [&](int kt, int half) {
#pragma unroll
    for (int j = 0; j < 2; ++j) {
      int c = (w * 2 + j) * 64 + l;
      int row = c >> 3, cc = c & 7;
      int gcc = cc ^ (row & 7);
      async_copy16(Kp + (size_t)(kt * 64 + row) * HD + gcc * 8,
                   &Ks[half][(w * 2 + j) * 512]);
      async_copy16(Vp + (size_t)row * SS + kt * 64 + gcc * 8,
                   &Vs[half][(w * 2 + j) * 512]);
    }
  };

  stage(0, 0);
  for (int kt = 0; kt < SS / 64; ++kt) {
    const int half = kt & 1;
    __syncthreads();
    if (kt + 1 < SS / 64) stage(kt + 1, half ^ 1);

    f32x4 st[2][4];
#pragma unroll
    for (int nt = 0; nt < 2; ++nt)
#pragma unroll
      for (int mt = 0; mt < 4; ++mt) st[nt][mt] = (f32x4)0.f;
#pragma unroll
    for (int kb = 0; kb < 2; ++kb)
#pragma unroll
      for (int mt = 0; mt < 4; ++mt) {
        int row = mt * 16 + ln;
        bf16x8 ka = *(const bf16x8*)(&Ks[half][row * 64 + (((kb * 4 + g) ^ (row & 7)) * 8)]);
        st[0][mt] = __builtin_amdgcn_mfma_f32_16x16x32_bf16(ka, qf[0][kb], st[0][mt], 0, 0, 0);
        st[1][mt] = __builtin_amdgcn_mfma_f32_16x16x32_bf16(ka, qf[1][kb], st[1][mt], 0, 0, 0);
      }

    // p = exp2(s'); pack bf16 pairs; write P to wave-private LDS scratch
#pragma unroll
    for (int nt = 0; nt < 2; ++nt) {
      const int q = nt * 16 + ln;
      const int qs = q & 7;
#pragma unroll
      for (int mt = 0; mt < 4; ++mt) {
        float p0 = fast_exp2(st[nt][mt][0]);
        float p1 = fast_exp2(st[nt][mt][1]);
        float p2 = fast_exp2(st[nt][mt][2]);
        float p3 = fast_exp2(st[nt][mt][3]);
        uint2 v2;
        v2.x = __builtin_amdgcn_perm(__float_as_uint(p1), __float_as_uint(p0), 0x07060302u);
        v2.y = __builtin_amdgcn_perm(__float_as_uint(p3), __float_as_uint(p2), 0x07060302u);
        rs[nt] += (p0 + p1) + (p2 + p3);
        int chunk = (2 * mt + (g >> 1)) ^ qs;
        *(uint2*)(pw + q * 128 + chunk * 16 + (g & 1) * 8) = v2;
      }
    }

#pragma unroll
    for (int kb = 0; kb < 2; ++kb) {
      bf16x8 pbv[2];
#pragma unroll
      for (int nt = 0; nt < 2; ++nt) {
        const int q = nt * 16 + ln;
        int chunk = (4 * kb + g) ^ (q & 7);
        pbv[nt] = *(const bf16x8*)(pw + q * 128 + chunk * 16);
      }
#pragma unroll
      for (int mt = 0; mt < 4; ++mt) {
        int row = mt * 16 + ln;
        bf16x8 va = *(const bf16x8*)(&Vs[half][row * 64 + (((kb * 4 + g) ^ (row & 7)) * 8)]);
        o[0][mt] = __builtin_amdgcn_mfma_f32_16x16x32_bf16(va, pbv[0], o[0][mt], 0, 0, 0);
        o[1][mt] = __builtin_amdgcn_mfma_f32_16x16x32_bf16(va, pbv[1], o[1][mt], 0, 0, 0);
      }
    }
  }

#pragma unroll
  for (int nt = 0; nt < 2; ++nt) {
    float lsum = rs[nt];
    lsum += __shfl_xor(lsum, 16, 64);
    lsum += __shfl_xor(lsum, 32, 64);
    float inv = 1.f / lsum;
    int srow = qt * 128 + w * 32 + nt * 16 + ln;
    unsigned short* cb = ctx + (size_t)(b * SS + srow) * DD + h * HD;
#pragma unroll
    for (int mt = 0; mt < 4; ++mt) {
      ushort4 u4;
      u4.x = f2bf(o[nt][mt][0] * inv);
      u4.y = f2bf(o[nt][mt][1] * inv);
      u4.z = f2bf(o[nt][mt][2] * inv);
      u4.w = f2bf(o[nt][mt][3] * inv);
      *(ushort4*)(cb + mt * 16 + 4 * g) = u4;
    }
  }
}

// ---------------------------------------------------------------------------
extern "C" void kernel_launch(void* const* d_in, const int* in_sizes, int n_in,
                              void* d_out, int out_size, void* d_ws, size_t ws_size,
                              hipStream_t stream) {
  const float* x  = (const float*)d_in[0];
  const float* Wq = (const float*)d_in[1];
  const float* bq = (const float*)d_in[2];
  const float* Wk = (const float*)d_in[3];
  const float* bk = (const float*)d_in[4];
  const float* Wv = (const float*)d_in[5];
  const float* bv = (const float*)d_in[6];
  const float* Wo = (const float*)d_in[7];
  const float* bo = (const float*)d_in[8];
  float* out = (float*)d_out;

  const size_t ELEMS = (size_t)BB * SS * DD;  // 4,194,304
  char* ws = (char*)d_ws;
  unsigned short* xb   = (unsigned short*)ws;  ws += ELEMS * 2;
  unsigned short* WqT  = (unsigned short*)ws;  ws += (size_t)DD * DD * 2;
  unsigned short* WkT  = (unsigned short*)ws;  ws += (size_t)DD * DD * 2;
  unsigned short* WvT  = (unsigned short*)ws;  ws += (size_t)DD * DD * 2;
  unsigned short* WoT  = (unsigned short*)ws;  ws += (size_t)DD * DD * 2;
  unsigned short* Qb   = (unsigned short*)ws;  ws += ELEMS * 2;
  unsigned short* Kb   = (unsigned short*)ws;  ws += ELEMS * 2;
  unsigned short* VbT  = (unsigned short*)ws;  ws += ELEMS * 2;
  unsigned short* ctxb = (unsigned short*)ws;  ws += ELEMS * 2;

  // fused prep: x->bf16 (4096 blocks) + 4 weight transposes (4096 blocks)
  prep_kernel<<<8192, 256, 0, stream>>>(x, xb, Wq, WqT, Wk, WkT, Wv, WvT, Wo, WoT);

  qkv_gemm_mfma<<<768, 256, 0, stream>>>(xb, WqT, WkT, WvT, bq, bk, bv,
                                         Qb, Kb, VbT);

  dim3 attn_grid(BB * HH, SS / 128);           // (32, 16) = 512 blocks
  flash_attn_mfma<<<attn_grid, 256, 0, stream>>>(Qb, Kb, VbT, ctxb);

  out_gemm_mfma<<<256, 256, 0, stream>>>(ctxb, WoT, bo, out);
}